// Round 1
// baseline (1414.067 us; speedup 1.0000x reference)
//
#include <hip/hip_runtime.h>
#include <math.h>

#define BB 4
#define SS 1024
#define DD 1024
#define HH 16
#define HDD 64
#define MTOT (BB*SS)   // 4096

// ---------------- GEMM: C = A[M,K] @ Bm[K,N] + bias ----------------
// BM=64, BN=64, BK=16, 256 threads, 4x4 micro-tile per thread.
// MODE 0: C = A@B + bias
// MODE 1: gate fusion: g = sigmoid(A@B + bias + trust[m]*wlast[n]); C = A[m,n] * g
//         (requires K == N == 1024, A is "attended")
template<int MODE>
__global__ __launch_bounds__(256)
void gemm_kernel(const float* __restrict__ A, const float* __restrict__ Bm,
                 const float* __restrict__ bias, float* __restrict__ C,
                 int M, int N, int K,
                 const float* __restrict__ trust,
                 const float* __restrict__ wlast)
{
    __shared__ float As[16][68];
    __shared__ float Bs[16][64];
    const int t  = threadIdx.x;
    const int tx = t & 15, ty = t >> 4;
    const int m0 = blockIdx.y * 64;
    const int n0 = blockIdx.x * 64;

    float acc[4][4] = {};

    for (int k0 = 0; k0 < K; k0 += 16) {
        // A tile 64x16 -> As[kk][i] (transposed)
        {
            const int i  = t >> 2;         // 0..63
            const int kk = (t & 3) * 4;    // 0,4,8,12
            const float4 av = *(const float4*)&A[(size_t)(m0 + i) * K + k0 + kk];
            As[kk+0][i] = av.x; As[kk+1][i] = av.y; As[kk+2][i] = av.z; As[kk+3][i] = av.w;
        }
        // B tile 16x64 -> Bs[kk][n]
        {
            const int kk = t >> 4;         // 0..15
            const int n4 = (t & 15) * 4;
            *(float4*)&Bs[kk][n4] = *(const float4*)&Bm[(size_t)(k0 + kk) * N + n0 + n4];
        }
        __syncthreads();
        #pragma unroll
        for (int kk = 0; kk < 16; ++kk) {
            const float4 av = *(const float4*)&As[kk][ty*4];
            const float a0 = av.x, a1 = av.y, a2 = av.z, a3 = av.w;
            #pragma unroll
            for (int j = 0; j < 4; ++j) {
                const float bv = Bs[kk][tx + 16*j];
                acc[0][j] += a0*bv;
                acc[1][j] += a1*bv;
                acc[2][j] += a2*bv;
                acc[3][j] += a3*bv;
            }
        }
        __syncthreads();
    }

    #pragma unroll
    for (int r = 0; r < 4; ++r) {
        const int m = m0 + ty*4 + r;
        #pragma unroll
        for (int j = 0; j < 4; ++j) {
            const int n = n0 + tx + 16*j;
            float c = acc[r][j] + bias[n];
            if (MODE == 1) {
                const float pre = c + trust[m]*wlast[n];
                const float g = 1.f/(1.f + expf(-pre));
                C[(size_t)m*N + n] = A[(size_t)m*K + n] * g;
            } else {
                C[(size_t)m*N + n] = c;
            }
        }
    }
}

// ---------------- Attention ----------------
// One block: 16 query rows for one (b,h). Scores strip kept in LDS (fp32),
// softmax in LDS, attn written once to global, PV from LDS.
__global__ __launch_bounds__(256)
void attn_kernel(const float* __restrict__ Q, const float* __restrict__ Km,
                 const float* __restrict__ V, const float* __restrict__ trust,
                 const int* __restrict__ mask,
                 const float* __restrict__ Wtp, const float* __restrict__ btp,
                 float* __restrict__ attnOut, float* __restrict__ attended)
{
    __shared__ float qs[16][68];
    __shared__ float kt[32][68];
    __shared__ float sc[16][1024];
    __shared__ float tqs[16];
    __shared__ float tks[32];
    __shared__ int   mq[16];

    const int t  = threadIdx.x;
    const int q0 = blockIdx.x * 16;
    const int h  = blockIdx.y;
    const int b  = blockIdx.z;

    // rank-1 trust-affinity constants (uniform scalar loop, cached)
    float c1 = 0.f, c2 = 0.f, c3 = 0.f;
    for (int d = 0; d < HDD; ++d) {
        const float w = Wtp[d], bt = btp[d];
        c1 += w*w; c2 += w*bt; c3 += bt*bt;
    }

    // load Q tile + trust + mask
    {
        const int i  = t >> 4;           // 0..15
        const int d4 = (t & 15) * 4;
        *(float4*)&qs[i][d4] =
            *(const float4*)&Q[((size_t)(b*SS + q0 + i))*DD + h*HDD + d4];
        if (t < 16) { tqs[t] = trust[b*SS + q0 + t]; mq[t] = mask[b*SS + q0 + t]; }
    }
    __syncthreads();

    // ---- scores ----
    const int qi = t >> 4;   // 0..15
    const int kl = t & 15;   // handles k = kl and kl+16 within each 32-tile
    for (int k0 = 0; k0 < SS; k0 += 32) {
        {
            const int i  = t >> 4;
            const int d4 = (t & 15) * 4;
            *(float4*)&kt[i][d4] =
                *(const float4*)&Km[((size_t)(b*SS + k0 + i))*DD + h*HDD + d4];
            *(float4*)&kt[i+16][d4] =
                *(const float4*)&Km[((size_t)(b*SS + k0 + i + 16))*DD + h*HDD + d4];
            if (t < 32) tks[t] = trust[b*SS + k0 + t];
        }
        __syncthreads();

        float s0 = 0.f, s1 = 0.f;
        #pragma unroll
        for (int d4 = 0; d4 < 64; d4 += 4) {
            const float4 qa = *(const float4*)&qs[qi][d4];
            const float4 ka = *(const float4*)&kt[kl][d4];
            const float4 kb = *(const float4*)&kt[kl+16][d4];
            s0 += qa.x*ka.x + qa.y*ka.y + qa.z*ka.z + qa.w*ka.w;
            s1 += qa.x*kb.x + qa.y*kb.y + qa.z*kb.z + qa.w*kb.w;
        }
        const float tq  = tqs[qi];
        const float tk0 = tks[kl], tk1 = tks[kl+16];
        const float ta0 = c1*tq*tk0 + c2*(tq+tk0) + c3;
        const float ta1 = c1*tq*tk1 + c2*(tq+tk1) + c3;
        s0 = s0*0.125f + 0.1f/(1.f + expf(-ta0));
        s1 = s1*0.125f + 0.1f/(1.f + expf(-ta1));
        if (mq[qi] == 0) { s0 = -1e9f; s1 = -1e9f; }
        sc[qi][k0 + kl]      = s0;
        sc[qi][k0 + kl + 16] = s1;
        __syncthreads();
    }

    // ---- softmax (16 lanes per row) + write attn ----
    {
        const int r = t >> 4;
        const int l = t & 15;
        float4* row4 = (float4*)sc[r];
        float mx = -1e30f;
        for (int j = l; j < 256; j += 16) {
            const float4 v = row4[j];
            mx = fmaxf(mx, fmaxf(fmaxf(v.x, v.y), fmaxf(v.z, v.w)));
        }
        #pragma unroll
        for (int m = 1; m < 16; m <<= 1) mx = fmaxf(mx, __shfl_xor(mx, m));
        float sum = 0.f;
        for (int j = l; j < 256; j += 16) {
            const float4 v = row4[j];
            sum += expf(v.x-mx) + expf(v.y-mx) + expf(v.z-mx) + expf(v.w-mx);
        }
        #pragma unroll
        for (int m = 1; m < 16; m <<= 1) sum += __shfl_xor(sum, m);
        const float inv = 1.f / sum;
        float* attnRow = attnOut + (((size_t)(b*HH + h))*SS + (q0 + r))*SS;
        for (int j = l; j < 256; j += 16) {
            float4 v = row4[j];
            v.x = expf(v.x-mx)*inv; v.y = expf(v.y-mx)*inv;
            v.z = expf(v.z-mx)*inv; v.w = expf(v.w-mx)*inv;
            row4[j] = v;
            *(float4*)&attnRow[j*4] = v;
        }
    }
    __syncthreads();

    // ---- PV: attended[q][hd] = sum_k p[q][k] * V[k][hd] ----
    {
        const int q  = t >> 4;
        const int hd = (t & 15) * 4;
        float4 acc = {0.f, 0.f, 0.f, 0.f};
        for (int k0 = 0; k0 < SS; k0 += 32) {
            const int i  = t >> 4;
            const int d4 = (t & 15) * 4;
            *(float4*)&kt[i][d4] =
                *(const float4*)&V[((size_t)(b*SS + k0 + i))*DD + h*HDD + d4];
            *(float4*)&kt[i+16][d4] =
                *(const float4*)&V[((size_t)(b*SS + k0 + i + 16))*DD + h*HDD + d4];
            __syncthreads();
            #pragma unroll
            for (int kk = 0; kk < 32; ++kk) {
                const float p = sc[q][k0 + kk];
                const float4 v = *(const float4*)&kt[kk][hd];
                acc.x += p*v.x; acc.y += p*v.y; acc.z += p*v.z; acc.w += p*v.w;
            }
            __syncthreads();
        }
        *(float4*)&attended[((size_t)(b*SS + q0 + q))*DD + h*HDD + hd] = acc;
    }
}

extern "C" void kernel_launch(void* const* d_in, const int* in_sizes, int n_in,
                              void* d_out, int out_size, void* d_ws, size_t ws_size,
                              hipStream_t stream) {
    const float* x     = (const float*)d_in[0];
    const float* trust = (const float*)d_in[1];
    const int*   mask  = (const int*)  d_in[2];
    const float* Wq    = (const float*)d_in[3];
    const float* bq    = (const float*)d_in[4];
    const float* Wk    = (const float*)d_in[5];
    const float* bk    = (const float*)d_in[6];
    const float* Wv    = (const float*)d_in[7];
    const float* bv    = (const float*)d_in[8];
    const float* Wtp   = (const float*)d_in[9];
    const float* btp   = (const float*)d_in[10];
    const float* Wg    = (const float*)d_in[11];
    const float* bg    = (const float*)d_in[12];
    const float* Wo    = (const float*)d_in[13];
    const float* bo    = (const float*)d_in[14];

    float* out     = (float*)d_out;                    // [B,S,D]
    float* attnOut = out + (size_t)MTOT * DD;          // [B,H,S,S]

    float* ws    = (float*)d_ws;
    float* Qw    = ws;                                 // 4096*1024
    float* Kw    = ws + (size_t)MTOT*DD;
    float* Vw    = ws + (size_t)2*MTOT*DD;
    float* Att   = ws + (size_t)3*MTOT*DD;
    float* Gated = ws;                                 // reuse Q slot (Q dead after attn)

    const dim3 gGrid(DD/64, MTOT/64);   // (16, 64)
    const dim3 blk(256);

    gemm_kernel<0><<<gGrid, blk, 0, stream>>>(x, Wq, bq, Qw, MTOT, DD, DD, nullptr, nullptr);
    gemm_kernel<0><<<gGrid, blk, 0, stream>>>(x, Wk, bk, Kw, MTOT, DD, DD, nullptr, nullptr);
    gemm_kernel<0><<<gGrid, blk, 0, stream>>>(x, Wv, bv, Vw, MTOT, DD, DD, nullptr, nullptr);

    attn_kernel<<<dim3(SS/16, HH, BB), blk, 0, stream>>>(
        Qw, Kw, Vw, trust, mask, Wtp, btp, attnOut, Att);

    // gate: uses first 1024 rows of Wg as B, last row via epilogue
    gemm_kernel<1><<<gGrid, blk, 0, stream>>>(Att, Wg, bg, Gated, MTOT, DD, DD,
                                              trust, Wg + (size_t)DD*DD);
    gemm_kernel<0><<<gGrid, blk, 0, stream>>>(Gated, Wo, bo, out, MTOT, DD, DD, nullptr, nullptr);
}

// Round 2
// 767.919 us; speedup vs baseline: 1.8414x; 1.8414x over previous
//
#include <hip/hip_runtime.h>
#include <math.h>

#define BB 4
#define SS 1024
#define DD 1024
#define HH 16
#define HDD 64
#define MTOT (BB*SS)   // 4096

typedef float  f32x4  __attribute__((ext_vector_type(4)));
typedef __bf16 bf16x8 __attribute__((ext_vector_type(8)));

__device__ __forceinline__ unsigned short f2bf(float f) {
    union { float f; unsigned u; } v; v.f = f;
    unsigned r = v.u + 0x7FFFu + ((v.u >> 16) & 1u);
    return (unsigned short)(r >> 16);
}
__device__ __forceinline__ f32x4 mfma16(bf16x8 a, bf16x8 b, f32x4 c) {
    return __builtin_amdgcn_mfma_f32_16x16x32_bf16(a, b, c, 0, 0, 0);
}

// ---------------- GEMM: C = A[M,K] @ Bm[K,N] + bias ----------------
// BM=64, BN=64, BK=16, 256 threads, 4x4 micro-tile (thread owns 4 consecutive n).
// MODE 0: fp32 out.  MODE 1: gate fusion (fp32 out).
// MODE 2: bf16 out, [m][n].  MODE 3: bf16 out transposed per-head [b][h][d][s].
template<int MODE>
__global__ __launch_bounds__(256)
void gemm_kernel(const float* __restrict__ A, const float* __restrict__ Bm,
                 const float* __restrict__ bias, void* __restrict__ Cout,
                 int M, int N, int K,
                 const float* __restrict__ trust, const float* __restrict__ wlast)
{
    __shared__ float As[16][68];
    __shared__ float Bs[16][64];
    const int t  = threadIdx.x;
    const int tx = t & 15, ty = t >> 4;
    const int m0 = blockIdx.y * 64, n0 = blockIdx.x * 64;

    float acc[4][4] = {};

    for (int k0 = 0; k0 < K; k0 += 16) {
        {
            const int i  = t >> 2;
            const int kk = (t & 3) * 4;
            f32x4 av = *(const f32x4*)&A[(size_t)(m0 + i) * K + k0 + kk];
            As[kk+0][i] = av[0]; As[kk+1][i] = av[1]; As[kk+2][i] = av[2]; As[kk+3][i] = av[3];
        }
        {
            const int kk = t >> 4;
            const int n4 = (t & 15) * 4;
            *(f32x4*)&Bs[kk][n4] = *(const f32x4*)&Bm[(size_t)(k0 + kk) * N + n0 + n4];
        }
        __syncthreads();
        #pragma unroll
        for (int kk = 0; kk < 16; ++kk) {
            f32x4 av = *(const f32x4*)&As[kk][ty*4];
            f32x4 bv = *(const f32x4*)&Bs[kk][tx*4];
            #pragma unroll
            for (int r = 0; r < 4; ++r)
                #pragma unroll
                for (int j = 0; j < 4; ++j)
                    acc[r][j] += av[r]*bv[j];
        }
        __syncthreads();
    }

    f32x4 b4 = *(const f32x4*)&bias[n0 + tx*4];

    if (MODE == 0) {
        float* C = (float*)Cout;
        #pragma unroll
        for (int r = 0; r < 4; ++r) {
            const int m = m0 + ty*4 + r;
            f32x4 o;
            #pragma unroll
            for (int j = 0; j < 4; ++j) o[j] = acc[r][j] + b4[j];
            *(f32x4*)&C[(size_t)m*N + n0 + tx*4] = o;
        }
    } else if (MODE == 1) {
        float* C = (float*)Cout;
        f32x4 w4 = *(const f32x4*)&wlast[n0 + tx*4];
        #pragma unroll
        for (int r = 0; r < 4; ++r) {
            const int m = m0 + ty*4 + r;
            const float tm = trust[m];
            f32x4 a4 = *(const f32x4*)&A[(size_t)m*K + n0 + tx*4];
            f32x4 o;
            #pragma unroll
            for (int j = 0; j < 4; ++j) {
                const float pre = acc[r][j] + b4[j] + tm*w4[j];
                const float g = 1.f/(1.f + __expf(-pre));
                o[j] = a4[j]*g;
            }
            *(f32x4*)&C[(size_t)m*N + n0 + tx*4] = o;
        }
    } else if (MODE == 2) {
        unsigned short* C = (unsigned short*)Cout;
        #pragma unroll
        for (int r = 0; r < 4; ++r) {
            const int m = m0 + ty*4 + r;
            ushort4 o;
            o.x = f2bf(acc[r][0] + b4[0]); o.y = f2bf(acc[r][1] + b4[1]);
            o.z = f2bf(acc[r][2] + b4[2]); o.w = f2bf(acc[r][3] + b4[3]);
            *(ushort4*)&C[(size_t)m*N + n0 + tx*4] = o;
        }
    } else { // MODE 3: Vt[b][h][d][s] bf16
        unsigned short* C = (unsigned short*)Cout;
        const int bb = m0 >> 10;            // m0 multiple of 64, S=1024
        const int s0 = (m0 & (SS-1)) + ty*4;
        #pragma unroll
        for (int j = 0; j < 4; ++j) {
            const int n = n0 + tx*4 + j;
            const int h = n >> 6, d = n & 63;
            ushort4 o;
            o.x = f2bf(acc[0][j] + b4[j]); o.y = f2bf(acc[1][j] + b4[j]);
            o.z = f2bf(acc[2][j] + b4[j]); o.w = f2bf(acc[3][j] + b4[j]);
            *(ushort4*)&C[(((size_t)bb*HH + h)*HDD + d)*SS + s0] = o;
        }
    }
}

// ---------------- Attention (MFMA bf16) ----------------
// Block: 16 q-rows for one (b,h); 4 waves; wave w owns keys [w*256, w*256+256).
// Scores in registers (16 x f32x4); softmax via shfl + tiny LDS cross-wave combine.
__global__ __launch_bounds__(256)
void attn_kernel(const unsigned short* __restrict__ Qb, const unsigned short* __restrict__ Kb,
                 const unsigned short* __restrict__ Vt, const float* __restrict__ trust,
                 const int* __restrict__ mask, const float* __restrict__ Wtp,
                 const float* __restrict__ btp, float* __restrict__ attnOut,
                 float* __restrict__ attended)
{
    __shared__ float tkbuf[1024];
    __shared__ float redA[4][16];
    __shared__ float redB[4][16];
    __shared__ int   mqv[16];
    __shared__ short pbuf[4][16][264];   // 33792 B; aliased as fp32 PV partials later

    const int t    = threadIdx.x;
    const int lane = t & 63, wave = t >> 6;
    const int l15  = lane & 15, l4 = lane >> 4;
    const int q0   = blockIdx.x * 16, h = blockIdx.y, b = blockIdx.z;
    const int wk0  = wave * 256;

    // rank-1 trust-affinity constants
    float c1 = 0.f, c2 = 0.f, c3 = 0.f;
    for (int d = 0; d < HDD; ++d) {
        const float w = Wtp[d], bt = btp[d];
        c1 += w*w; c2 += w*bt; c3 += bt*bt;
    }

    *(f32x4*)&tkbuf[t*4] = *(const f32x4*)&trust[b*SS + t*4];
    if (t < 16) mqv[t] = mask[b*SS + q0 + t];

    // Q A-fragments (row = l15, d = l4*8+j), 16B contiguous
    const unsigned short* Qp = Qb + ((size_t)(b*SS + q0 + l15))*DD + h*HDD + l4*8;
    bf16x8 qf0 = *(const bf16x8*)Qp;
    bf16x8 qf1 = *(const bf16x8*)(Qp + 32);
    __syncthreads();

    // ---- QK^T: 16 key-subtiles of 16, K=64 as 2 MFMAs ----
    f32x4 sacc[16];
    #pragma unroll
    for (int tt = 0; tt < 16; ++tt) sacc[tt] = (f32x4){0.f,0.f,0.f,0.f};

    const unsigned short* Kbase = Kb + ((size_t)(b*SS + wk0 + l15))*DD + h*HDD + l4*8;
    #pragma unroll
    for (int tt = 0; tt < 16; ++tt) {
        const unsigned short* Kp = Kbase + (size_t)tt*(16*DD);
        bf16x8 kf0 = *(const bf16x8*)Kp;
        bf16x8 kf1 = *(const bf16x8*)(Kp + 32);
        sacc[tt] = mfma16(qf0, kf0, sacc[tt]);
        sacc[tt] = mfma16(qf1, kf1, sacc[tt]);
    }

    // ---- bias + mask + row-max ----
    float tq[4]; int mrow[4];
    #pragma unroll
    for (int r = 0; r < 4; ++r) { tq[r] = tkbuf[q0 + l4*4 + r]; mrow[r] = mqv[l4*4 + r]; }

    float mx[4] = {-3e38f, -3e38f, -3e38f, -3e38f};
    #pragma unroll
    for (int tt = 0; tt < 16; ++tt) {
        const float tk = tkbuf[wk0 + tt*16 + l15];
        #pragma unroll
        for (int r = 0; r < 4; ++r) {
            const float ta = c1*tq[r]*tk + c2*(tq[r] + tk) + c3;
            float s = sacc[tt][r]*0.125f + 0.1f/(1.f + __expf(-ta));
            s = mrow[r] ? s : -1e9f;
            sacc[tt][r] = s;
            mx[r] = fmaxf(mx[r], s);
        }
    }
    #pragma unroll
    for (int r = 0; r < 4; ++r)
        #pragma unroll
        for (int xm = 1; xm < 16; xm <<= 1) mx[r] = fmaxf(mx[r], __shfl_xor(mx[r], xm));
    if (l15 == 0) {
        #pragma unroll
        for (int r = 0; r < 4; ++r) redA[wave][l4*4 + r] = mx[r];
    }
    __syncthreads();

    float mxa[4];
    #pragma unroll
    for (int r = 0; r < 4; ++r) {
        const int row = l4*4 + r;
        mxa[r] = fmaxf(fmaxf(redA[0][row], redA[1][row]), fmaxf(redA[2][row], redA[3][row]));
    }

    // ---- exp + row-sum ----
    float sum[4] = {0.f, 0.f, 0.f, 0.f};
    #pragma unroll
    for (int tt = 0; tt < 16; ++tt)
        #pragma unroll
        for (int r = 0; r < 4; ++r) {
            const float p = __expf(sacc[tt][r] - mxa[r]);
            sacc[tt][r] = p;
            sum[r] += p;
        }
    #pragma unroll
    for (int r = 0; r < 4; ++r)
        #pragma unroll
        for (int xm = 1; xm < 16; xm <<= 1) sum[r] += __shfl_xor(sum[r], xm);
    if (l15 == 0) {
        #pragma unroll
        for (int r = 0; r < 4; ++r) redB[wave][l4*4 + r] = sum[r];
    }
    __syncthreads();

    float inv[4];
    #pragma unroll
    for (int r = 0; r < 4; ++r) {
        const int row = l4*4 + r;
        inv[r] = 1.f/(redB[0][row] + redB[1][row] + redB[2][row] + redB[3][row]);
    }

    // ---- write attn (global) + P (LDS bf16) ----
    float* attnBase = attnOut + ((size_t)(b*HH + h))*SS*SS;
    #pragma unroll
    for (int tt = 0; tt < 16; ++tt)
        #pragma unroll
        for (int r = 0; r < 4; ++r) {
            const int row = l4*4 + r;
            const float pn = sacc[tt][r]*inv[r];
            attnBase[(size_t)(q0 + row)*SS + wk0 + tt*16 + l15] = pn;
            pbuf[wave][row][tt*16 + l15] = (short)f2bf(pn);
        }
    __syncthreads();

    // ---- PV: wave's partial attended[16][64] over its 256-key strip ----
    f32x4 pv[4];
    #pragma unroll
    for (int nt = 0; nt < 4; ++nt) pv[nt] = (f32x4){0.f,0.f,0.f,0.f};

    const unsigned short* Vbase = Vt + (((size_t)(b*HH + h))*HDD + l15)*SS + wk0 + l4*8;
    #pragma unroll
    for (int t2 = 0; t2 < 8; ++t2) {
        bf16x8 af = *(const bf16x8*)&pbuf[wave][l15][t2*32 + l4*8];
        #pragma unroll
        for (int nt = 0; nt < 4; ++nt) {
            bf16x8 bf = *(const bf16x8*)(Vbase + (size_t)nt*16*SS + t2*32);
            pv[nt] = mfma16(af, bf, pv[nt]);
        }
    }
    __syncthreads();

    // ---- cross-wave reduce through LDS (alias pbuf) ----
    float* pvbuf = (float*)&pbuf[0][0][0];
    float* pw = pvbuf + wave*1024;
    #pragma unroll
    for (int nt = 0; nt < 4; ++nt)
        #pragma unroll
        for (int r = 0; r < 4; ++r)
            pw[(l4*4 + r)*64 + nt*16 + l15] = pv[nt][r];
    __syncthreads();

    {
        const int q = t >> 4, d0 = (t & 15)*4;
        f32x4 s = *(f32x4*)&pvbuf[q*64 + d0];
        s += *(f32x4*)&pvbuf[1024 + q*64 + d0];
        s += *(f32x4*)&pvbuf[2048 + q*64 + d0];
        s += *(f32x4*)&pvbuf[3072 + q*64 + d0];
        *(f32x4*)&attended[((size_t)(b*SS + q0 + q))*DD + h*HDD + d0] = s;
    }
}

extern "C" void kernel_launch(void* const* d_in, const int* in_sizes, int n_in,
                              void* d_out, int out_size, void* d_ws, size_t ws_size,
                              hipStream_t stream) {
    const float* x     = (const float*)d_in[0];
    const float* trust = (const float*)d_in[1];
    const int*   mask  = (const int*)  d_in[2];
    const float* Wq    = (const float*)d_in[3];
    const float* bq    = (const float*)d_in[4];
    const float* Wk    = (const float*)d_in[5];
    const float* bk    = (const float*)d_in[6];
    const float* Wv    = (const float*)d_in[7];
    const float* bv    = (const float*)d_in[8];
    const float* Wtp   = (const float*)d_in[9];
    const float* btp   = (const float*)d_in[10];
    const float* Wg    = (const float*)d_in[11];
    const float* bg    = (const float*)d_in[12];
    const float* Wo    = (const float*)d_in[13];
    const float* bo    = (const float*)d_in[14];

    float* out     = (float*)d_out;
    float* attnOut = out + (size_t)MTOT * DD;

    char* ws = (char*)d_ws;
    unsigned short* Qbf = (unsigned short*)ws;                       // 8 MB
    unsigned short* Kbf = (unsigned short*)(ws + (size_t)8*1024*1024);
    unsigned short* Vt  = (unsigned short*)(ws + (size_t)16*1024*1024);
    float* Att   = (float*)(ws + (size_t)24*1024*1024);              // 16 MB fp32
    float* Gated = (float*)ws;                                       // reuse Q/K (dead)

    const dim3 gGrid(DD/64, MTOT/64);
    const dim3 blk(256);

    gemm_kernel<2><<<gGrid, blk, 0, stream>>>(x, Wq, bq, Qbf, MTOT, DD, DD, nullptr, nullptr);
    gemm_kernel<2><<<gGrid, blk, 0, stream>>>(x, Wk, bk, Kbf, MTOT, DD, DD, nullptr, nullptr);
    gemm_kernel<3><<<gGrid, blk, 0, stream>>>(x, Wv, bv, Vt,  MTOT, DD, DD, nullptr, nullptr);

    attn_kernel<<<dim3(SS/16, HH, BB), blk, 0, stream>>>(
        Qbf, Kbf, Vt, trust, mask, Wtp, btp, attnOut, Att);

    gemm_kernel<1><<<gGrid, blk, 0, stream>>>(Att, Wg, bg, Gated, MTOT, DD, DD,
                                              trust, Wg + (size_t)DD*DD);
    gemm_kernel<0><<<gGrid, blk, 0, stream>>>(Gated, Wo, bo, out, MTOT, DD, DD, nullptr, nullptr);
}

// Round 4
// 350.308 us; speedup vs baseline: 4.0366x; 2.1921x over previous
//
#include <hip/hip_runtime.h>
#include <math.h>

#define BB 4
#define SS 1024
#define DD 1024
#define HH 16
#define HDD 64
#define MTOT (BB*SS)   // 4096
#define MB (1024*1024)

typedef float  f32x4  __attribute__((ext_vector_type(4)));
typedef __bf16 bf16x8 __attribute__((ext_vector_type(8)));
typedef unsigned short u16;

__device__ __forceinline__ unsigned short f2bf(float f) {
    union { float f; unsigned u; } v; v.f = f;
    unsigned r = v.u + 0x7FFFu + ((v.u >> 16) & 1u);
    return (unsigned short)(r >> 16);
}
__device__ __forceinline__ float bf2f(unsigned short u) {
    union { unsigned u; float f; } v; v.u = ((unsigned)u) << 16;
    return v.f;
}
__device__ __forceinline__ f32x4 mfma16(bf16x8 a, bf16x8 b, f32x4 c) {
    return __builtin_amdgcn_mfma_f32_16x16x32_bf16(a, b, c, 0, 0, 0);
}
__device__ __forceinline__ void gload16(const void* g, void* l) {
    __builtin_amdgcn_global_load_lds(
        (const __attribute__((address_space(1))) void*)g,
        (__attribute__((address_space(3))) void*)l, 16, 0, 0);
}

// ---------------- split: fp32 -> bf16 hi/lo ----------------
__global__ void split_kernel(const float* __restrict__ in, u16* __restrict__ hi,
                             u16* __restrict__ lo, int n4)
{
    for (int i = blockIdx.x*blockDim.x + threadIdx.x; i < n4; i += gridDim.x*blockDim.x) {
        f32x4 v = ((const f32x4*)in)[i];
        ushort4 h4, l4;
        h4.x = f2bf(v[0]); l4.x = f2bf(v[0] - bf2f(h4.x));
        h4.y = f2bf(v[1]); l4.y = f2bf(v[1] - bf2f(h4.y));
        h4.z = f2bf(v[2]); l4.z = f2bf(v[2] - bf2f(h4.z));
        h4.w = f2bf(v[3]); l4.w = f2bf(v[3] - bf2f(h4.w));
        ((ushort4*)hi)[i] = h4; ((ushort4*)lo)[i] = l4;
    }
}

// ---------------- transpose + split: W[k][n] fp32 -> WT hi/lo [n][k] bf16 ----------------
__global__ __launch_bounds__(256)
void tsplit_kernel(const float* __restrict__ W, u16* __restrict__ hT, u16* __restrict__ lT)
{
    __shared__ float tile[64][65];
    const int t  = threadIdx.x;
    const int k0 = blockIdx.y * 64, n0 = blockIdx.x * 64;
    const int r  = t >> 4, c4 = (t & 15) * 4;
    #pragma unroll
    for (int rr = 0; rr < 4; ++rr) {
        const int k = r + rr*16;
        f32x4 v = *(const f32x4*)&W[(size_t)(k0 + k)*1024 + n0 + c4];
        tile[k][c4+0] = v[0]; tile[k][c4+1] = v[1]; tile[k][c4+2] = v[2]; tile[k][c4+3] = v[3];
    }
    __syncthreads();
    #pragma unroll
    for (int rr = 0; rr < 4; ++rr) {
        const int nl = r + rr*16;
        ushort4 hh, ll;
        {
            float v;
            v = tile[c4+0][nl]; hh.x = f2bf(v); ll.x = f2bf(v - bf2f(hh.x));
            v = tile[c4+1][nl]; hh.y = f2bf(v); ll.y = f2bf(v - bf2f(hh.y));
            v = tile[c4+2][nl]; hh.z = f2bf(v); ll.z = f2bf(v - bf2f(hh.z));
            v = tile[c4+3][nl]; hh.w = f2bf(v); ll.w = f2bf(v - bf2f(hh.w));
        }
        *(ushort4*)&hT[(size_t)(n0 + nl)*1024 + k0 + c4] = hh;
        *(ushort4*)&lT[(size_t)(n0 + nl)*1024 + k0 + c4] = ll;
    }
}

// ---------------- split-bf16 MFMA GEMM ----------------
// C[M][N] = (Ah+Al)[M][K=1024] @ (Bh+Bl)^T[N][K=1024]   (3-pass: AhBh + AhBl + AlBh)
// 128x128 tile, BK=64, 4 waves (2x2), double-buffered LDS via global_load_lds,
// XOR-swizzled chunks (c ^= row&7) for conflict-free ds_read_b128.
// MODE 0: fp32 out + bias[n].   MODE 1: gate fusion, bf16 hi/lo out.
// MODE 2: bf16 hi out + bias[n].  MODE 3: bf16 hi out + bias[m] (transposed-V use).
template<int MODE>
__global__ __launch_bounds__(256)
void mgemm(const u16* __restrict__ Ah, const u16* __restrict__ Al,
           const u16* __restrict__ Bh, const u16* __restrict__ Bl,
           const float* __restrict__ bias,
           float* __restrict__ outF, u16* __restrict__ outH, u16* __restrict__ outL,
           int M, int N,
           const float* __restrict__ trust, const float* __restrict__ wlast,
           const u16* __restrict__ attH, const u16* __restrict__ attL)
{
    __shared__ u16 lds[2][4][128*64];   // 128 KB: [buf][Ah,Al,Bh,Bl][row*64 + elem]

    const int t    = threadIdx.x;
    const int lane = t & 63, wave = t >> 6;
    const int l15  = lane & 15, l4 = lane >> 4;
    const int wr   = wave >> 1, wc = wave & 1;
    const int w64  = wave << 6;
    const int m0   = blockIdx.y * 128, n0 = blockIdx.x * 128;

    const u16* src0 = Ah + (size_t)m0*1024;
    const u16* src1 = Al + (size_t)m0*1024;
    const u16* src2 = Bh + (size_t)n0*1024;
    const u16* src3 = Bl + (size_t)n0*1024;

    f32x4 acc[4][4];
    #pragma unroll
    for (int i = 0; i < 4; ++i)
        #pragma unroll
        for (int j = 0; j < 4; ++j) acc[i][j] = (f32x4){0.f,0.f,0.f,0.f};

#define STAGE(BUF, KOFF) do {                                                  \
    const u16* s_[4] = { src0 + (KOFF), src1 + (KOFF), src2 + (KOFF), src3 + (KOFF) }; \
    _Pragma("unroll")                                                          \
    for (int tl_ = 0; tl_ < 4; ++tl_) {                                        \
        _Pragma("unroll")                                                      \
        for (int it_ = 0; it_ < 4; ++it_) {                                    \
            const int idx_ = it_*256 + t;                                      \
            const int row_ = idx_ >> 3;                                        \
            const int c_   = (idx_ & 7) ^ (row_ & 7);                          \
            gload16(s_[tl_] + (size_t)row_*1024 + c_*8,                        \
                    &lds[BUF][tl_][(it_*256 + w64)*8]);                        \
        }                                                                      \
    }                                                                          \
} while(0)

#define COMPUTE(BUF) do {                                                      \
    _Pragma("unroll")                                                          \
    for (int kk_ = 0; kk_ < 2; ++kk_) {                                        \
        const int cb_ = (kk_<<2) + l4;                                         \
        bf16x8 ah_[4], al_[4];                                                 \
        _Pragma("unroll")                                                      \
        for (int i_ = 0; i_ < 4; ++i_) {                                       \
            const int row_ = (wr<<6) + (i_<<4) + l15;                          \
            const int off_ = (row_<<6) + ((cb_ ^ (row_&7)) << 3);              \
            ah_[i_] = *(const bf16x8*)&lds[BUF][0][off_];                      \
            al_[i_] = *(const bf16x8*)&lds[BUF][1][off_];                      \
        }                                                                      \
        _Pragma("unroll")                                                      \
        for (int j_ = 0; j_ < 4; ++j_) {                                       \
            const int row_ = (wc<<6) + (j_<<4) + l15;                          \
            const int off_ = (row_<<6) + ((cb_ ^ (row_&7)) << 3);              \
            bf16x8 bh_ = *(const bf16x8*)&lds[BUF][2][off_];                   \
            bf16x8 bl_ = *(const bf16x8*)&lds[BUF][3][off_];                   \
            _Pragma("unroll")                                                  \
            for (int i_ = 0; i_ < 4; ++i_) {                                   \
                acc[i_][j_] = mfma16(ah_[i_], bh_, acc[i_][j_]);               \
                acc[i_][j_] = mfma16(ah_[i_], bl_, acc[i_][j_]);               \
                acc[i_][j_] = mfma16(al_[i_], bh_, acc[i_][j_]);               \
            }                                                                  \
        }                                                                      \
    }                                                                          \
} while(0)

    // Double-buffered pipeline: stage NEXT tile into buf cur^1 while computing
    // buf cur. __syncthreads() (compiler drains vmcnt before s_barrier) makes
    // the staged buffer visible before it becomes the compute buffer.
    STAGE(0, 0);
    __syncthreads();
    int cur = 0;
    for (int s = 0; s < 15; ++s) {
        if (cur == 0) STAGE(1, (s+1)*64);
        else          STAGE(0, (s+1)*64);
        COMPUTE(cur);
        __syncthreads();
        cur ^= 1;
    }
    COMPUTE(cur);
#undef STAGE
#undef COMPUTE

    // ---- epilogue ----
    #pragma unroll
    for (int i = 0; i < 4; ++i)
        #pragma unroll
        for (int j = 0; j < 4; ++j)
            #pragma unroll
            for (int r = 0; r < 4; ++r) {
                const int m = m0 + (wr<<6) + (i<<4) + (l4<<2) + r;
                const int n = n0 + (wc<<6) + (j<<4) + l15;
                const float v = acc[i][j][r];
                if (MODE == 0) {
                    outF[(size_t)m*N + n] = v + bias[n];
                } else if (MODE == 2) {
                    outH[(size_t)m*N + n] = f2bf(v + bias[n]);
                } else if (MODE == 3) {
                    outH[(size_t)m*N + n] = f2bf(v + bias[m]);
                } else {
                    const float pre = v + bias[n] + trust[m]*wlast[n];
                    const float g = 1.f/(1.f + __expf(-pre));
                    const float att = bf2f(attH[(size_t)m*N + n]) + bf2f(attL[(size_t)m*N + n]);
                    const float gated = att*g;
                    const unsigned short hb = f2bf(gated);
                    outH[(size_t)m*N + n] = hb;
                    outL[(size_t)m*N + n] = f2bf(gated - bf2f(hb));
                }
            }
}

// ---------------- Attention (MFMA bf16) ----------------
__global__ __launch_bounds__(256)
void attn_kernel(const u16* __restrict__ Qb, const u16* __restrict__ Kb,
                 const u16* __restrict__ Vt, const float* __restrict__ trust,
                 const int* __restrict__ mask, const float* __restrict__ Wtp,
                 const float* __restrict__ btp, float* __restrict__ attnOut,
                 u16* __restrict__ attH, u16* __restrict__ attL)
{
    __shared__ float tkbuf[1024];
    __shared__ float redA[4][16];
    __shared__ float redB[4][16];
    __shared__ int   mqv[16];
    __shared__ short pbuf[4][16][264];

    const int t    = threadIdx.x;
    const int lane = t & 63, wave = t >> 6;
    const int l15  = lane & 15, l4 = lane >> 4;
    const int q0   = blockIdx.x * 16, h = blockIdx.y, b = blockIdx.z;
    const int wk0  = wave * 256;

    float c1 = 0.f, c2 = 0.f, c3 = 0.f;
    for (int d = 0; d < HDD; ++d) {
        const float w = Wtp[d], bt = btp[d];
        c1 += w*w; c2 += w*bt; c3 += bt*bt;
    }

    *(f32x4*)&tkbuf[t*4] = *(const f32x4*)&trust[b*SS + t*4];
    if (t < 16) mqv[t] = mask[b*SS + q0 + t];

    const u16* Qp = Qb + ((size_t)(b*SS + q0 + l15))*DD + h*HDD + l4*8;
    bf16x8 qf0 = *(const bf16x8*)Qp;
    bf16x8 qf1 = *(const bf16x8*)(Qp + 32);
    __syncthreads();

    f32x4 sacc[16];
    #pragma unroll
    for (int tt = 0; tt < 16; ++tt) sacc[tt] = (f32x4){0.f,0.f,0.f,0.f};

    const u16* Kbase = Kb + ((size_t)(b*SS + wk0 + l15))*DD + h*HDD + l4*8;
    #pragma unroll
    for (int tt = 0; tt < 16; ++tt) {
        const u16* Kp = Kbase + (size_t)tt*(16*DD);
        bf16x8 kf0 = *(const bf16x8*)Kp;
        bf16x8 kf1 = *(const bf16x8*)(Kp + 32);
        sacc[tt] = mfma16(qf0, kf0, sacc[tt]);
        sacc[tt] = mfma16(qf1, kf1, sacc[tt]);
    }

    float tq[4]; int mrow[4];
    #pragma unroll
    for (int r = 0; r < 4; ++r) { tq[r] = tkbuf[q0 + l4*4 + r]; mrow[r] = mqv[l4*4 + r]; }

    float mx[4] = {-3e38f, -3e38f, -3e38f, -3e38f};
    #pragma unroll
    for (int tt = 0; tt < 16; ++tt) {
        const float tk = tkbuf[wk0 + tt*16 + l15];
        #pragma unroll
        for (int r = 0; r < 4; ++r) {
            const float ta = c1*tq[r]*tk + c2*(tq[r] + tk) + c3;
            float s = sacc[tt][r]*0.125f + 0.1f/(1.f + __expf(-ta));
            s = mrow[r] ? s : -1e9f;
            sacc[tt][r] = s;
            mx[r] = fmaxf(mx[r], s);
        }
    }
    #pragma unroll
    for (int r = 0; r < 4; ++r)
        #pragma unroll
        for (int xm = 1; xm < 16; xm <<= 1) mx[r] = fmaxf(mx[r], __shfl_xor(mx[r], xm));
    if (l15 == 0) {
        #pragma unroll
        for (int r = 0; r < 4; ++r) redA[wave][l4*4 + r] = mx[r];
    }
    __syncthreads();

    float mxa[4];
    #pragma unroll
    for (int r = 0; r < 4; ++r) {
        const int row = l4*4 + r;
        mxa[r] = fmaxf(fmaxf(redA[0][row], redA[1][row]), fmaxf(redA[2][row], redA[3][row]));
    }

    float sum[4] = {0.f, 0.f, 0.f, 0.f};
    #pragma unroll
    for (int tt = 0; tt < 16; ++tt)
        #pragma unroll
        for (int r = 0; r < 4; ++r) {
            const float p = __expf(sacc[tt][r] - mxa[r]);
            sacc[tt][r] = p;
            sum[r] += p;
        }
    #pragma unroll
    for (int r = 0; r < 4; ++r)
        #pragma unroll
        for (int xm = 1; xm < 16; xm <<= 1) sum[r] += __shfl_xor(sum[r], xm);
    if (l15 == 0) {
        #pragma unroll
        for (int r = 0; r < 4; ++r) redB[wave][l4*4 + r] = sum[r];
    }
    __syncthreads();

    float inv[4];
    #pragma unroll
    for (int r = 0; r < 4; ++r) {
        const int row = l4*4 + r;
        inv[r] = 1.f/(redB[0][row] + redB[1][row] + redB[2][row] + redB[3][row]);
    }

    float* attnBase = attnOut + ((size_t)(b*HH + h))*SS*SS;
    #pragma unroll
    for (int tt = 0; tt < 16; ++tt)
        #pragma unroll
        for (int r = 0; r < 4; ++r) {
            const int row = l4*4 + r;
            const float pn = sacc[tt][r]*inv[r];
            attnBase[(size_t)(q0 + row)*SS + wk0 + tt*16 + l15] = pn;
            pbuf[wave][row][tt*16 + l15] = (short)f2bf(pn);
        }
    __syncthreads();

    f32x4 pv[4];
    #pragma unroll
    for (int nt = 0; nt < 4; ++nt) pv[nt] = (f32x4){0.f,0.f,0.f,0.f};

    // Vt layout: [d_glob = h*64+d][m = b*1024 + s]
    const u16* Vbase = Vt + ((size_t)(h*HDD + l15))*MTOT + b*SS + wk0 + l4*8;
    #pragma unroll
    for (int t2 = 0; t2 < 8; ++t2) {
        bf16x8 af = *(const bf16x8*)&pbuf[wave][l15][t2*32 + l4*8];
        #pragma unroll
        for (int nt = 0; nt < 4; ++nt) {
            bf16x8 bf = *(const bf16x8*)(Vbase + (size_t)nt*16*MTOT + t2*32);
            pv[nt] = mfma16(af, bf, pv[nt]);
        }
    }
    __syncthreads();

    float* pvbuf = (float*)&pbuf[0][0][0];
    float* pw = pvbuf + wave*1024;
    #pragma unroll
    for (int nt = 0; nt < 4; ++nt)
        #pragma unroll
        for (int r = 0; r < 4; ++r)
            pw[(l4*4 + r)*64 + nt*16 + l15] = pv[nt][r];
    __syncthreads();

    {
        const int q = t >> 4, d0 = (t & 15)*4;
        f32x4 s = *(f32x4*)&pvbuf[q*64 + d0];
        s += *(f32x4*)&pvbuf[1024 + q*64 + d0];
        s += *(f32x4*)&pvbuf[2048 + q*64 + d0];
        s += *(f32x4*)&pvbuf[3072 + q*64 + d0];
        ushort4 oh, ol;
        oh.x = f2bf(s[0]); ol.x = f2bf(s[0] - bf2f(oh.x));
        oh.y = f2bf(s[1]); ol.y = f2bf(s[1] - bf2f(oh.y));
        oh.z = f2bf(s[2]); ol.z = f2bf(s[2] - bf2f(oh.z));
        oh.w = f2bf(s[3]); ol.w = f2bf(s[3] - bf2f(oh.w));
        const size_t off = ((size_t)(b*SS + q0 + q))*DD + h*HDD + d0;
        *(ushort4*)&attH[off] = oh;
        *(ushort4*)&attL[off] = ol;
    }
}

extern "C" void kernel_launch(void* const* d_in, const int* in_sizes, int n_in,
                              void* d_out, int out_size, void* d_ws, size_t ws_size,
                              hipStream_t stream) {
    const float* x     = (const float*)d_in[0];
    const float* trust = (const float*)d_in[1];
    const int*   mask  = (const int*)  d_in[2];
    const float* Wq    = (const float*)d_in[3];
    const float* bq    = (const float*)d_in[4];
    const float* Wk    = (const float*)d_in[5];
    const float* bk    = (const float*)d_in[6];
    const float* Wv    = (const float*)d_in[7];
    const float* bv    = (const float*)d_in[8];
    const float* Wtp   = (const float*)d_in[9];
    const float* btp   = (const float*)d_in[10];
    const float* Wg    = (const float*)d_in[11];
    const float* bg    = (const float*)d_in[12];
    const float* Wo    = (const float*)d_in[13];
    const float* bo    = (const float*)d_in[14];

    float* out     = (float*)d_out;
    float* attnOut = out + (size_t)MTOT * DD;

    char* ws = (char*)d_ws;
    u16* xh   = (u16*)(ws + (size_t)0*MB);    // 8 MB -> attH later
    u16* xl   = (u16*)(ws + (size_t)8*MB);    // 8 MB -> attL later
    u16* WqTh = (u16*)(ws + (size_t)16*MB);
    u16* WqTl = (u16*)(ws + (size_t)18*MB);
    u16* WkTh = (u16*)(ws + (size_t)20*MB);
    u16* WkTl = (u16*)(ws + (size_t)22*MB);
    u16* WvTh = (u16*)(ws + (size_t)24*MB);
    u16* WvTl = (u16*)(ws + (size_t)26*MB);
    u16* WgTh = (u16*)(ws + (size_t)28*MB);
    u16* WgTl = (u16*)(ws + (size_t)30*MB);
    u16* WoTh = (u16*)(ws + (size_t)32*MB);
    u16* WoTl = (u16*)(ws + (size_t)34*MB);
    u16* Qbf  = (u16*)(ws + (size_t)36*MB);   // 8 MB -> Gh later
    u16* Kbf  = (u16*)(ws + (size_t)44*MB);   // 8 MB -> Gl later
    u16* Vt   = (u16*)(ws + (size_t)52*MB);   // 8 MB
    u16* attH = xh;
    u16* attL = xl;
    u16* Gh   = Qbf;
    u16* Gl   = Kbf;

    const dim3 blk(256);
    const dim3 tgrid(16, 16);

    split_kernel<<<2048, blk, 0, stream>>>(x, xh, xl, MTOT*DD/4);
    tsplit_kernel<<<tgrid, blk, 0, stream>>>(Wq, WqTh, WqTl);
    tsplit_kernel<<<tgrid, blk, 0, stream>>>(Wk, WkTh, WkTl);
    tsplit_kernel<<<tgrid, blk, 0, stream>>>(Wv, WvTh, WvTl);
    tsplit_kernel<<<tgrid, blk, 0, stream>>>(Wg, WgTh, WgTl);
    tsplit_kernel<<<tgrid, blk, 0, stream>>>(Wo, WoTh, WoTl);

    // Q, K: C[m][n] = x @ Wq/Wk  (bf16 out)
    mgemm<2><<<dim3(DD/128, MTOT/128), blk, 0, stream>>>(
        xh, xl, WqTh, WqTl, bq, nullptr, Qbf, nullptr, MTOT, DD,
        nullptr, nullptr, nullptr, nullptr);
    mgemm<2><<<dim3(DD/128, MTOT/128), blk, 0, stream>>>(
        xh, xl, WkTh, WkTl, bk, nullptr, Kbf, nullptr, MTOT, DD,
        nullptr, nullptr, nullptr, nullptr);
    // V^T: C[d_glob][m] = WvT @ x^T  (bf16 out, bias by row)
    mgemm<3><<<dim3(MTOT/128, DD/128), blk, 0, stream>>>(
        WvTh, WvTl, xh, xl, bv, nullptr, Vt, nullptr, DD, MTOT,
        nullptr, nullptr, nullptr, nullptr);

    attn_kernel<<<dim3(SS/16, HH, BB), blk, 0, stream>>>(
        Qbf, Kbf, Vt, trust, mask, Wtp, btp, attnOut, attH, attL);

    // gate: gated = attended * sigmoid(attended@Wg[0:1024] + bg + trust*wlast)
    mgemm<1><<<dim3(DD/128, MTOT/128), blk, 0, stream>>>(
        attH, attL, WgTh, WgTl, bg, nullptr, Gh, Gl, MTOT, DD,
        trust, Wg + (size_t)DD*DD, attH, attL);
    // out = gated @ Wo + bo  (fp32)
    mgemm<0><<<dim3(DD/128, MTOT/128), blk, 0, stream>>>(
        Gh, Gl, WoTh, WoTl, bo, out, nullptr, nullptr, MTOT, DD,
        nullptr, nullptr, nullptr, nullptr);
}

// Round 5
// 337.613 us; speedup vs baseline: 4.1884x; 1.0376x over previous
//
#include <hip/hip_runtime.h>
#include <math.h>

#define BB 4
#define SS 1024
#define DD 1024
#define HH 16
#define HDD 64
#define MTOT (BB*SS)   // 4096
#define MB (1024*1024)

typedef float  f32x4  __attribute__((ext_vector_type(4)));
typedef __bf16 bf16x8 __attribute__((ext_vector_type(8)));
typedef unsigned short u16;

__device__ __forceinline__ unsigned short f2bf(float f) {
    union { float f; unsigned u; } v; v.f = f;
    unsigned r = v.u + 0x7FFFu + ((v.u >> 16) & 1u);
    return (unsigned short)(r >> 16);
}
__device__ __forceinline__ float bf2f(unsigned short u) {
    union { unsigned u; float f; } v; v.u = ((unsigned)u) << 16;
    return v.f;
}
__device__ __forceinline__ f32x4 mfma16(bf16x8 a, bf16x8 b, f32x4 c) {
    return __builtin_amdgcn_mfma_f32_16x16x32_bf16(a, b, c, 0, 0, 0);
}
__device__ __forceinline__ void gload16(const void* g, void* l) {
    __builtin_amdgcn_global_load_lds(
        (const __attribute__((address_space(1))) void*)g,
        (__attribute__((address_space(3))) void*)l, 16, 0, 0);
}

// ---------------- split: fp32 -> bf16 hi/lo ----------------
__global__ void split_kernel(const float* __restrict__ in, u16* __restrict__ hi,
                             u16* __restrict__ lo, int n4)
{
    for (int i = blockIdx.x*blockDim.x + threadIdx.x; i < n4; i += gridDim.x*blockDim.x) {
        f32x4 v = ((const f32x4*)in)[i];
        ushort4 h4, l4;
        h4.x = f2bf(v[0]); l4.x = f2bf(v[0] - bf2f(h4.x));
        h4.y = f2bf(v[1]); l4.y = f2bf(v[1] - bf2f(h4.y));
        h4.z = f2bf(v[2]); l4.z = f2bf(v[2] - bf2f(h4.z));
        h4.w = f2bf(v[3]); l4.w = f2bf(v[3] - bf2f(h4.w));
        ((ushort4*)hi)[i] = h4; ((ushort4*)lo)[i] = l4;
    }
}

// ---------------- transpose + split: W[k][n] fp32 -> WT hi/lo [n][k] bf16 ----------------
__global__ __launch_bounds__(256)
void tsplit_kernel(const float* __restrict__ W, u16* __restrict__ hT, u16* __restrict__ lT)
{
    __shared__ float tile[64][65];
    const int t  = threadIdx.x;
    const int k0 = blockIdx.y * 64, n0 = blockIdx.x * 64;
    const int r  = t >> 4, c4 = (t & 15) * 4;
    #pragma unroll
    for (int rr = 0; rr < 4; ++rr) {
        const int k = r + rr*16;
        f32x4 v = *(const f32x4*)&W[(size_t)(k0 + k)*1024 + n0 + c4];
        tile[k][c4+0] = v[0]; tile[k][c4+1] = v[1]; tile[k][c4+2] = v[2]; tile[k][c4+3] = v[3];
    }
    __syncthreads();
    #pragma unroll
    for (int rr = 0; rr < 4; ++rr) {
        const int nl = r + rr*16;
        ushort4 hh, ll;
        {
            float v;
            v = tile[c4+0][nl]; hh.x = f2bf(v); ll.x = f2bf(v - bf2f(hh.x));
            v = tile[c4+1][nl]; hh.y = f2bf(v); ll.y = f2bf(v - bf2f(hh.y));
            v = tile[c4+2][nl]; hh.z = f2bf(v); ll.z = f2bf(v - bf2f(hh.z));
            v = tile[c4+3][nl]; hh.w = f2bf(v); ll.w = f2bf(v - bf2f(hh.w));
        }
        *(ushort4*)&hT[(size_t)(n0 + nl)*1024 + k0 + c4] = hh;
        *(ushort4*)&lT[(size_t)(n0 + nl)*1024 + k0 + c4] = ll;
    }
}

// ---------------- trust-affinity rank-1 constants ----------------
__global__ void tconst_kernel(const float* __restrict__ Wtp, const float* __restrict__ btp,
                              float* __restrict__ out3)
{
    const int l = threadIdx.x;   // 64 threads
    const float w = Wtp[l], b = btp[l];
    float a = w*w, m = w*b, c = b*b;
    #pragma unroll
    for (int s = 32; s; s >>= 1) {
        a += __shfl_down(a, s);
        m += __shfl_down(m, s);
        c += __shfl_down(c, s);
    }
    if (l == 0) { out3[0] = a; out3[1] = m; out3[2] = c; }
}

// ---------------- split-bf16 MFMA GEMM ----------------
// C[M][N] = (Ah+Al)[M][K=1024] @ (Bh+Bl)^T[N][K=1024]   (3-pass: AhBh + AhBl + AlBh)
template<int MODE>
__global__ __launch_bounds__(256)
void mgemm(const u16* __restrict__ Ah, const u16* __restrict__ Al,
           const u16* __restrict__ Bh, const u16* __restrict__ Bl,
           const float* __restrict__ bias,
           float* __restrict__ outF, u16* __restrict__ outH, u16* __restrict__ outL,
           int M, int N,
           const float* __restrict__ trust, const float* __restrict__ wlast,
           const u16* __restrict__ attH, const u16* __restrict__ attL)
{
    __shared__ u16 lds[2][4][128*64];   // 128 KB

    const int t    = threadIdx.x;
    const int lane = t & 63, wave = t >> 6;
    const int l15  = lane & 15, l4 = lane >> 4;
    const int wr   = wave >> 1, wc = wave & 1;
    const int w64  = wave << 6;
    const int m0   = blockIdx.y * 128, n0 = blockIdx.x * 128;

    const u16* src0 = Ah + (size_t)m0*1024;
    const u16* src1 = Al + (size_t)m0*1024;
    const u16* src2 = Bh + (size_t)n0*1024;
    const u16* src3 = Bl + (size_t)n0*1024;

    f32x4 acc[4][4];
    #pragma unroll
    for (int i = 0; i < 4; ++i)
        #pragma unroll
        for (int j = 0; j < 4; ++j) acc[i][j] = (f32x4){0.f,0.f,0.f,0.f};

#define STAGE(BUF, KOFF) do {                                                  \
    const u16* s_[4] = { src0 + (KOFF), src1 + (KOFF), src2 + (KOFF), src3 + (KOFF) }; \
    _Pragma("unroll")                                                          \
    for (int tl_ = 0; tl_ < 4; ++tl_) {                                        \
        _Pragma("unroll")                                                      \
        for (int it_ = 0; it_ < 4; ++it_) {                                    \
            const int idx_ = it_*256 + t;                                      \
            const int row_ = idx_ >> 3;                                        \
            const int c_   = (idx_ & 7) ^ (row_ & 7);                          \
            gload16(s_[tl_] + (size_t)row_*1024 + c_*8,                        \
                    &lds[BUF][tl_][(it_*256 + w64)*8]);                        \
        }                                                                      \
    }                                                                          \
} while(0)

#define COMPUTE(BUF) do {                                                      \
    _Pragma("unroll")                                                          \
    for (int kk_ = 0; kk_ < 2; ++kk_) {                                        \
        const int cb_ = (kk_<<2) + l4;                                         \
        bf16x8 ah_[4], al_[4];                                                 \
        _Pragma("unroll")                                                      \
        for (int i_ = 0; i_ < 4; ++i_) {                                       \
            const int row_ = (wr<<6) + (i_<<4) + l15;                          \
            const int off_ = (row_<<6) + ((cb_ ^ (row_&7)) << 3);              \
            ah_[i_] = *(const bf16x8*)&lds[BUF][0][off_];                      \
            al_[i_] = *(const bf16x8*)&lds[BUF][1][off_];                      \
        }                                                                      \
        _Pragma("unroll")                                                      \
        for (int j_ = 0; j_ < 4; ++j_) {                                       \
            const int row_ = (wc<<6) + (j_<<4) + l15;                          \
            const int off_ = (row_<<6) + ((cb_ ^ (row_&7)) << 3);              \
            bf16x8 bh_ = *(const bf16x8*)&lds[BUF][2][off_];                   \
            bf16x8 bl_ = *(const bf16x8*)&lds[BUF][3][off_];                   \
            _Pragma("unroll")                                                  \
            for (int i_ = 0; i_ < 4; ++i_) {                                   \
                acc[i_][j_] = mfma16(ah_[i_], bh_, acc[i_][j_]);               \
                acc[i_][j_] = mfma16(ah_[i_], bl_, acc[i_][j_]);               \
                acc[i_][j_] = mfma16(al_[i_], bh_, acc[i_][j_]);               \
            }                                                                  \
        }                                                                      \
    }                                                                          \
} while(0)

    STAGE(0, 0);
    __syncthreads();
    int cur = 0;
    for (int s = 0; s < 15; ++s) {
        if (cur == 0) STAGE(1, (s+1)*64);
        else          STAGE(0, (s+1)*64);
        COMPUTE(cur);
        __syncthreads();
        cur ^= 1;
    }
    COMPUTE(cur);
#undef STAGE
#undef COMPUTE

    // ---- epilogue ----
    #pragma unroll
    for (int i = 0; i < 4; ++i)
        #pragma unroll
        for (int j = 0; j < 4; ++j)
            #pragma unroll
            for (int r = 0; r < 4; ++r) {
                const int m = m0 + (wr<<6) + (i<<4) + (l4<<2) + r;
                const int n = n0 + (wc<<6) + (j<<4) + l15;
                const float v = acc[i][j][r];
                if (MODE == 0) {
                    outF[(size_t)m*N + n] = v + bias[n];
                } else if (MODE == 2) {
                    outH[(size_t)m*N + n] = f2bf(v + bias[n]);
                } else if (MODE == 3) {
                    outH[(size_t)m*N + n] = f2bf(v + bias[m]);
                } else {
                    const float pre = v + bias[n] + trust[m]*wlast[n];
                    const float g = 1.f/(1.f + __expf(-pre));
                    const float att = bf2f(attH[(size_t)m*N + n]) + bf2f(attL[(size_t)m*N + n]);
                    const float gated = att*g;
                    const unsigned short hb = f2bf(gated);
                    outH[(size_t)m*N + n] = hb;
                    outL[(size_t)m*N + n] = f2bf(gated - bf2f(hb));
                }
            }
}

// ---------------- Attention v2 (MFMA bf16, LDS-staged coalesced attn write) ----------------
// Block: 16 q rows x (b,h), 512 threads / 8 waves; wave w owns keys [w*128, w*128+128).
// Unnormalized p staged fp32 in 64KB LDS (chunk-XOR swizzle c^=row&7); attn written
// by block-cooperative f32x4 streaming (512B contiguous per 32 lanes); PV reads
// unnormalized P and scales by 1/sum at the end.
__global__ __launch_bounds__(512, 4)
void attn_kernel(const u16* __restrict__ Qb, const u16* __restrict__ Kb,
                 const u16* __restrict__ Vt, const float* __restrict__ trust,
                 const int* __restrict__ mask, const float* __restrict__ tconst,
                 float* __restrict__ attnOut, u16* __restrict__ attH, u16* __restrict__ attL)
{
    __shared__ float P[16*1024];      // 64 KB score/P strip (also aliased for PV reduce)
    __shared__ float tkbuf[1024];
    __shared__ float redA[8][16];
    __shared__ float redB[8][16];
    __shared__ int   mqv[16];

    const int t    = threadIdx.x;
    const int lane = t & 63, wave = t >> 6;     // 8 waves
    const int l15  = lane & 15, l4 = lane >> 4;
    const int q0   = blockIdx.x * 16, h = blockIdx.y, b = blockIdx.z;
    const int wk0  = wave * 128;

    const float c1 = tconst[0], c2 = tconst[1], c3 = tconst[2];

    if (t < 256) *(f32x4*)&tkbuf[t*4] = *(const f32x4*)&trust[b*SS + t*4];
    if (t < 16) mqv[t] = mask[b*SS + q0 + t];

    const u16* Qp = Qb + ((size_t)(b*SS + q0 + l15))*DD + h*HDD + l4*8;
    bf16x8 qf0 = *(const bf16x8*)Qp;
    bf16x8 qf1 = *(const bf16x8*)(Qp + 32);
    __syncthreads();

    // ---- QK^T: 8 key tiles of 16 per wave ----
    f32x4 sacc[8];
    #pragma unroll
    for (int tt = 0; tt < 8; ++tt) sacc[tt] = (f32x4){0.f,0.f,0.f,0.f};

    const u16* Kbase = Kb + ((size_t)(b*SS + wk0 + l15))*DD + h*HDD + l4*8;
    #pragma unroll
    for (int tt = 0; tt < 8; ++tt) {
        const u16* Kp = Kbase + (size_t)tt*(16*DD);
        bf16x8 kf0 = *(const bf16x8*)Kp;
        bf16x8 kf1 = *(const bf16x8*)(Kp + 32);
        sacc[tt] = mfma16(qf0, kf0, sacc[tt]);
        sacc[tt] = mfma16(qf1, kf1, sacc[tt]);
    }

    // ---- bias + mask + row-max ----
    float tq[4]; int mrow[4];
    #pragma unroll
    for (int r = 0; r < 4; ++r) { tq[r] = tkbuf[q0 + l4*4 + r]; mrow[r] = mqv[l4*4 + r]; }

    float mx[4] = {-3e38f, -3e38f, -3e38f, -3e38f};
    #pragma unroll
    for (int tt = 0; tt < 8; ++tt) {
        const float tk = tkbuf[wk0 + tt*16 + l15];
        #pragma unroll
        for (int r = 0; r < 4; ++r) {
            const float ta = c1*tq[r]*tk + c2*(tq[r] + tk) + c3;
            float s = sacc[tt][r]*0.125f + 0.1f/(1.f + __expf(-ta));
            s = mrow[r] ? s : -1e9f;
            sacc[tt][r] = s;
            mx[r] = fmaxf(mx[r], s);
        }
    }
    #pragma unroll
    for (int r = 0; r < 4; ++r)
        #pragma unroll
        for (int xm = 1; xm < 16; xm <<= 1) mx[r] = fmaxf(mx[r], __shfl_xor(mx[r], xm));
    if (l15 == 0) {
        #pragma unroll
        for (int r = 0; r < 4; ++r) redA[wave][l4*4 + r] = mx[r];
    }
    __syncthreads();

    float mxa[4];
    #pragma unroll
    for (int r = 0; r < 4; ++r) {
        const int row = l4*4 + r;
        float m = redA[0][row];
        #pragma unroll
        for (int w = 1; w < 8; ++w) m = fmaxf(m, redA[w][row]);
        mxa[r] = m;
    }

    // ---- exp + row-sum; store UNNORMALIZED p to LDS (swizzled) ----
    float sum[4] = {0.f, 0.f, 0.f, 0.f};
    #pragma unroll
    for (int tt = 0; tt < 8; ++tt) {
        const int k = wk0 + tt*16 + l15;
        const int c = k >> 2, j = k & 3;
        #pragma unroll
        for (int r = 0; r < 4; ++r) {
            const int row = l4*4 + r;
            const float p = __expf(sacc[tt][r] - mxa[r]);
            sum[r] += p;
            P[row*1024 + ((c ^ (row & 7)) << 2) + j] = p;
        }
    }
    #pragma unroll
    for (int r = 0; r < 4; ++r)
        #pragma unroll
        for (int xm = 1; xm < 16; xm <<= 1) sum[r] += __shfl_xor(sum[r], xm);
    if (l15 == 0) {
        #pragma unroll
        for (int r = 0; r < 4; ++r) redB[wave][l4*4 + r] = sum[r];
    }
    __syncthreads();

    // ---- stream attn to global (coalesced f32x4, normalized on the fly) ----
    {
        const int row = t >> 5;            // 16 rows, 32 threads each
        const int cl  = t & 31;
        float s8 = 0.f;
        #pragma unroll
        for (int w = 0; w < 8; ++w) s8 += redB[w][row];
        const float iv = 1.f / s8;
        float* gRow = attnOut + ((size_t)(b*HH + h))*SS*SS + (size_t)(q0 + row)*SS;
        #pragma unroll
        for (int i = 0; i < 8; ++i) {
            const int c = cl + i*32;
            f32x4 v = *(f32x4*)&P[row*1024 + ((c ^ (row & 7)) << 2)];
            v *= iv;
            *(f32x4*)&gRow[c*4] = v;
        }
    }

    // ---- per-thread inverse sums for PV rows ----
    float inv4[4];
    #pragma unroll
    for (int r = 0; r < 4; ++r) {
        const int row = l4*4 + r;
        float s8 = 0.f;
        #pragma unroll
        for (int w = 0; w < 8; ++w) s8 += redB[w][row];
        inv4[r] = 1.f / s8;
    }

    // ---- PV: wave's 128-key strip, unnormalized P (bf16-cvt on the fly) ----
    f32x4 pv[4];
    #pragma unroll
    for (int nt = 0; nt < 4; ++nt) pv[nt] = (f32x4){0.f,0.f,0.f,0.f};

    const u16* Vbase = Vt + ((size_t)(h*HDD + l15))*MTOT + b*SS + wk0 + l4*8;
    #pragma unroll
    for (int t2 = 0; t2 < 4; ++t2) {
        const int k  = wk0 + t2*32 + l4*8;
        const int c0 = k >> 2;
        f32x4 a0 = *(f32x4*)&P[l15*1024 + (((c0    ) ^ (l15 & 7)) << 2)];
        f32x4 a1 = *(f32x4*)&P[l15*1024 + (((c0 + 1) ^ (l15 & 7)) << 2)];
        bf16x8 af;
        af[0] = (__bf16)a0[0]; af[1] = (__bf16)a0[1]; af[2] = (__bf16)a0[2]; af[3] = (__bf16)a0[3];
        af[4] = (__bf16)a1[0]; af[5] = (__bf16)a1[1]; af[6] = (__bf16)a1[2]; af[7] = (__bf16)a1[3];
        #pragma unroll
        for (int nt = 0; nt < 4; ++nt) {
            bf16x8 bf = *(const bf16x8*)(Vbase + (size_t)nt*16*MTOT + t2*32);
            pv[nt] = mfma16(af, bf, pv[nt]);
        }
    }
    __syncthreads();   // all P reads done before aliasing

    // ---- cross-wave reduce through LDS (alias P), scaled by 1/sum ----
    float* pw = P + wave*1024;
    #pragma unroll
    for (int nt = 0; nt < 4; ++nt)
        #pragma unroll
        for (int r = 0; r < 4; ++r)
            pw[(l4*4 + r)*64 + nt*16 + l15] = pv[nt][r] * inv4[r];
    __syncthreads();

    {
        const int q = t >> 5, d0 = (t & 31)*2;
        float sx = 0.f, sy = 0.f;
        #pragma unroll
        for (int w = 0; w < 8; ++w) {
            float2 v = *(float2*)&P[w*1024 + q*64 + d0];
            sx += v.x; sy += v.y;
        }
        const size_t off = ((size_t)(b*SS + q0 + q))*DD + h*HDD + d0;
        const unsigned short h0 = f2bf(sx), h1 = f2bf(sy);
        ushort2 hh = {h0, h1};
        ushort2 ll = {f2bf(sx - bf2f(h0)), f2bf(sy - bf2f(h1))};
        *(ushort2*)&attH[off] = hh;
        *(ushort2*)&attL[off] = ll;
    }
}

extern "C" void kernel_launch(void* const* d_in, const int* in_sizes, int n_in,
                              void* d_out, int out_size, void* d_ws, size_t ws_size,
                              hipStream_t stream) {
    const float* x     = (const float*)d_in[0];
    const float* trust = (const float*)d_in[1];
    const int*   mask  = (const int*)  d_in[2];
    const float* Wq    = (const float*)d_in[3];
    const float* bq    = (const float*)d_in[4];
    const float* Wk    = (const float*)d_in[5];
    const float* bk    = (const float*)d_in[6];
    const float* Wv    = (const float*)d_in[7];
    const float* bv    = (const float*)d_in[8];
    const float* Wtp   = (const float*)d_in[9];
    const float* btp   = (const float*)d_in[10];
    const float* Wg    = (const float*)d_in[11];
    const float* bg    = (const float*)d_in[12];
    const float* Wo    = (const float*)d_in[13];
    const float* bo    = (const float*)d_in[14];

    float* out     = (float*)d_out;
    float* attnOut = out + (size_t)MTOT * DD;

    char* ws = (char*)d_ws;
    u16* xh   = (u16*)(ws + (size_t)0*MB);    // 8 MB -> attH later
    u16* xl   = (u16*)(ws + (size_t)8*MB);    // 8 MB -> attL later
    u16* WqTh = (u16*)(ws + (size_t)16*MB);
    u16* WqTl = (u16*)(ws + (size_t)18*MB);
    u16* WkTh = (u16*)(ws + (size_t)20*MB);
    u16* WkTl = (u16*)(ws + (size_t)22*MB);
    u16* WvTh = (u16*)(ws + (size_t)24*MB);
    u16* WvTl = (u16*)(ws + (size_t)26*MB);
    u16* WgTh = (u16*)(ws + (size_t)28*MB);
    u16* WgTl = (u16*)(ws + (size_t)30*MB);
    u16* WoTh = (u16*)(ws + (size_t)32*MB);
    u16* WoTl = (u16*)(ws + (size_t)34*MB);
    u16* Qbf  = (u16*)(ws + (size_t)36*MB);   // 8 MB -> Gh later
    u16* Kbf  = (u16*)(ws + (size_t)44*MB);   // 8 MB -> Gl later
    u16* Vt   = (u16*)(ws + (size_t)52*MB);   // 8 MB
    float* tconst = (float*)(ws + (size_t)60*MB);
    u16* attH = xh;
    u16* attL = xl;
    u16* Gh   = Qbf;
    u16* Gl   = Kbf;

    const dim3 blk(256);
    const dim3 tgrid(16, 16);

    tconst_kernel<<<1, 64, 0, stream>>>(Wtp, btp, tconst);
    split_kernel<<<2048, blk, 0, stream>>>(x, xh, xl, MTOT*DD/4);
    tsplit_kernel<<<tgrid, blk, 0, stream>>>(Wq, WqTh, WqTl);
    tsplit_kernel<<<tgrid, blk, 0, stream>>>(Wk, WkTh, WkTl);
    tsplit_kernel<<<tgrid, blk, 0, stream>>>(Wv, WvTh, WvTl);
    tsplit_kernel<<<tgrid, blk, 0, stream>>>(Wg, WgTh, WgTl);
    tsplit_kernel<<<tgrid, blk, 0, stream>>>(Wo, WoTh, WoTl);

    // Q, K: C[m][n] = x @ Wq/Wk  (bf16 out)
    mgemm<2><<<dim3(DD/128, MTOT/128), blk, 0, stream>>>(
        xh, xl, WqTh, WqTl, bq, nullptr, Qbf, nullptr, MTOT, DD,
        nullptr, nullptr, nullptr, nullptr);
    mgemm<2><<<dim3(DD/128, MTOT/128), blk, 0, stream>>>(
        xh, xl, WkTh, WkTl, bk, nullptr, Kbf, nullptr, MTOT, DD,
        nullptr, nullptr, nullptr, nullptr);
    // V^T: C[d_glob][m] = WvT @ x^T  (bf16 out, bias by row)
    mgemm<3><<<dim3(MTOT/128, DD/128), blk, 0, stream>>>(
        WvTh, WvTl, xh, xl, bv, nullptr, Vt, nullptr, DD, MTOT,
        nullptr, nullptr, nullptr, nullptr);

    attn_kernel<<<dim3(SS/16, HH, BB), dim3(512), 0, stream>>>(
        Qbf, Kbf, Vt, trust, mask, tconst, attnOut, attH, attL);

    // gate: gated = attended * sigmoid(attended@Wg[0:1024] + bg + trust*wlast)
    mgemm<1><<<dim3(DD/128, MTOT/128), blk, 0, stream>>>(
        attH, attL, WgTh, WgTl, bg, nullptr, Gh, Gl, MTOT, DD,
        trust, Wg + (size_t)DD*DD, attH, attL);
    // out = gated @ Wo + bo  (fp32)
    mgemm<0><<<dim3(DD/128, MTOT/128), blk, 0, stream>>>(
        Gh, Gl, WoTh, WoTl, bo, out, nullptr, nullptr, MTOT, DD,
        nullptr, nullptr, nullptr, nullptr);
}

// Round 6
// 314.958 us; speedup vs baseline: 4.4897x; 1.0719x over previous
//
#include <hip/hip_runtime.h>
#include <math.h>

#define BB 4
#define SS 1024
#define DD 1024
#define HH 16
#define HDD 64
#define MTOT (BB*SS)   // 4096
#define MB (1024*1024)

typedef float  f32x4  __attribute__((ext_vector_type(4)));
typedef __bf16 bf16x8 __attribute__((ext_vector_type(8)));
typedef unsigned short u16;

__device__ __forceinline__ unsigned short f2bf(float f) {
    union { float f; unsigned u; } v; v.f = f;
    unsigned r = v.u + 0x7FFFu + ((v.u >> 16) & 1u);
    return (unsigned short)(r >> 16);
}
__device__ __forceinline__ float bf2f(unsigned short u) {
    union { unsigned u; float f; } v; v.u = ((unsigned)u) << 16;
    return v.f;
}
__device__ __forceinline__ f32x4 mfma16(bf16x8 a, bf16x8 b, f32x4 c) {
    return __builtin_amdgcn_mfma_f32_16x16x32_bf16(a, b, c, 0, 0, 0);
}
__device__ __forceinline__ void gload16(const void* g, void* l) {
    __builtin_amdgcn_global_load_lds(
        (const __attribute__((address_space(1))) void*)g,
        (__attribute__((address_space(3))) void*)l, 16, 0, 0);
}

// ---------------- split: fp32 -> bf16 hi/lo ----------------
__global__ void split_kernel(const float* __restrict__ in, u16* __restrict__ hi,
                             u16* __restrict__ lo, int n4)
{
    for (int i = blockIdx.x*blockDim.x + threadIdx.x; i < n4; i += gridDim.x*blockDim.x) {
        f32x4 v = ((const f32x4*)in)[i];
        ushort4 h4, l4;
        h4.x = f2bf(v[0]); l4.x = f2bf(v[0] - bf2f(h4.x));
        h4.y = f2bf(v[1]); l4.y = f2bf(v[1] - bf2f(h4.y));
        h4.z = f2bf(v[2]); l4.z = f2bf(v[2] - bf2f(h4.z));
        h4.w = f2bf(v[3]); l4.w = f2bf(v[3] - bf2f(h4.w));
        ((ushort4*)hi)[i] = h4; ((ushort4*)lo)[i] = l4;
    }
}

// ---------------- transpose + split: W[k][n] fp32 -> WT hi (+opt lo) [n][k] bf16 --------
__global__ __launch_bounds__(256)
void tsplit_kernel(const float* __restrict__ W, u16* __restrict__ hT, u16* __restrict__ lT)
{
    __shared__ float tile[64][65];
    const int t  = threadIdx.x;
    const int k0 = blockIdx.y * 64, n0 = blockIdx.x * 64;
    const int r  = t >> 4, c4 = (t & 15) * 4;
    #pragma unroll
    for (int rr = 0; rr < 4; ++rr) {
        const int k = r + rr*16;
        f32x4 v = *(const f32x4*)&W[(size_t)(k0 + k)*1024 + n0 + c4];
        tile[k][c4+0] = v[0]; tile[k][c4+1] = v[1]; tile[k][c4+2] = v[2]; tile[k][c4+3] = v[3];
    }
    __syncthreads();
    #pragma unroll
    for (int rr = 0; rr < 4; ++rr) {
        const int nl = r + rr*16;
        ushort4 hh, ll;
        {
            float v;
            v = tile[c4+0][nl]; hh.x = f2bf(v); ll.x = f2bf(v - bf2f(hh.x));
            v = tile[c4+1][nl]; hh.y = f2bf(v); ll.y = f2bf(v - bf2f(hh.y));
            v = tile[c4+2][nl]; hh.z = f2bf(v); ll.z = f2bf(v - bf2f(hh.z));
            v = tile[c4+3][nl]; hh.w = f2bf(v); ll.w = f2bf(v - bf2f(hh.w));
        }
        *(ushort4*)&hT[(size_t)(n0 + nl)*1024 + k0 + c4] = hh;
        if (lT) *(ushort4*)&lT[(size_t)(n0 + nl)*1024 + k0 + c4] = ll;
    }
}

// ---------------- trust-affinity rank-1 constants ----------------
__global__ void tconst_kernel(const float* __restrict__ Wtp, const float* __restrict__ btp,
                              float* __restrict__ out3)
{
    const int l = threadIdx.x;   // 64 threads
    const float w = Wtp[l], b = btp[l];
    float a = w*w, m = w*b, c = b*b;
    #pragma unroll
    for (int s = 32; s; s >>= 1) {
        a += __shfl_down(a, s);
        m += __shfl_down(m, s);
        c += __shfl_down(c, s);
    }
    if (l == 0) { out3[0] = a; out3[1] = m; out3[2] = c; }
}

// ---------------- trust bias table: T[b][q][k] = bf16(0.1*sigmoid(ta)) ----------------
__global__ __launch_bounds__(256)
void tbias_kernel(const float* __restrict__ trust, const float* __restrict__ tconst,
                  u16* __restrict__ T)
{
    const int b = blockIdx.y;
    const int q = blockIdx.x;
    const float tq = trust[b*SS + q];
    const float c1 = tconst[0], c2 = tconst[1], c3 = tconst[2];
    const int k0 = threadIdx.x * 4;
    f32x4 tk = *(const f32x4*)&trust[b*SS + k0];
    ushort4 o;
    #pragma unroll
    for (int j = 0; j < 4; ++j) {
        const float ta = c1*tq*tk[j] + c2*(tq + tk[j]) + c3;
        const float v  = 0.1f/(1.f + __expf(-ta));
        ((u16*)&o)[j] = f2bf(v);
    }
    *(ushort4*)&T[((size_t)b*SS + q)*SS + k0] = o;
}

// ---------------- split-bf16 MFMA GEMM ----------------
// PASSES=3: AhBh + AhBl + AlBh   (full split, stages 4 tiles, 128KB LDS)
// PASSES=2: AhBh + AlBh          (drop weight-lo, stages 3 tiles,  96KB LDS)
// PASSES=1: AhBh                 (plain bf16,     stages 2 tiles,  64KB LDS)
template<int MODE, int PASSES>
__global__ __launch_bounds__(256)
void mgemm(const u16* __restrict__ Ah, const u16* __restrict__ Al,
           const u16* __restrict__ Bh, const u16* __restrict__ Bl,
           const float* __restrict__ bias,
           float* __restrict__ outF, u16* __restrict__ outH, u16* __restrict__ outL,
           int M, int N,
           const float* __restrict__ trust, const float* __restrict__ wlast,
           const u16* __restrict__ attH, const u16* __restrict__ attL)
{
    constexpr int NT   = (PASSES == 3) ? 4 : (PASSES == 2) ? 3 : 2;
    constexpr int BIDX = (PASSES == 1) ? 1 : 2;
    __shared__ u16 lds[2][NT][128*64];

    const int t    = threadIdx.x;
    const int lane = t & 63, wave = t >> 6;
    const int l15  = lane & 15, l4 = lane >> 4;
    const int wr   = wave >> 1, wc = wave & 1;
    const int w64  = wave << 6;
    const int m0   = blockIdx.y * 128, n0 = blockIdx.x * 128;

    const u16* srcs[NT];
    srcs[0] = Ah + (size_t)m0*1024;
    if (PASSES >= 2) srcs[1] = Al + (size_t)m0*1024;
    srcs[BIDX] = Bh + (size_t)n0*1024;
    if (PASSES == 3) srcs[3] = Bl + (size_t)n0*1024;

    f32x4 acc[4][4];
    #pragma unroll
    for (int i = 0; i < 4; ++i)
        #pragma unroll
        for (int j = 0; j < 4; ++j) acc[i][j] = (f32x4){0.f,0.f,0.f,0.f};

#define STAGE(BUF, KOFF) do {                                                  \
    _Pragma("unroll")                                                          \
    for (int tl_ = 0; tl_ < NT; ++tl_) {                                       \
        _Pragma("unroll")                                                      \
        for (int it_ = 0; it_ < 4; ++it_) {                                    \
            const int idx_ = it_*256 + t;                                      \
            const int row_ = idx_ >> 3;                                        \
            const int c_   = (idx_ & 7) ^ (row_ & 7);                          \
            gload16(srcs[tl_] + (KOFF) + (size_t)row_*1024 + c_*8,             \
                    &lds[BUF][tl_][(it_*256 + w64)*8]);                        \
        }                                                                      \
    }                                                                          \
} while(0)

#define COMPUTE(BUF) do {                                                      \
    _Pragma("unroll")                                                          \
    for (int kk_ = 0; kk_ < 2; ++kk_) {                                        \
        const int cb_ = (kk_<<2) + l4;                                         \
        bf16x8 ah_[4], al_[4];                                                 \
        _Pragma("unroll")                                                      \
        for (int i_ = 0; i_ < 4; ++i_) {                                       \
            const int row_ = (wr<<6) + (i_<<4) + l15;                          \
            const int off_ = (row_<<6) + ((cb_ ^ (row_&7)) << 3);              \
            ah_[i_] = *(const bf16x8*)&lds[BUF][0][off_];                      \
            if (PASSES >= 2) al_[i_] = *(const bf16x8*)&lds[BUF][1][off_];     \
        }                                                                      \
        _Pragma("unroll")                                                      \
        for (int j_ = 0; j_ < 4; ++j_) {                                       \
            const int row_ = (wc<<6) + (j_<<4) + l15;                          \
            const int off_ = (row_<<6) + ((cb_ ^ (row_&7)) << 3);              \
            bf16x8 bh_ = *(const bf16x8*)&lds[BUF][BIDX][off_];                \
            bf16x8 bl_;                                                        \
            if (PASSES == 3) bl_ = *(const bf16x8*)&lds[BUF][3][off_];         \
            _Pragma("unroll")                                                  \
            for (int i_ = 0; i_ < 4; ++i_) {                                   \
                acc[i_][j_] = mfma16(ah_[i_], bh_, acc[i_][j_]);               \
                if (PASSES == 3) acc[i_][j_] = mfma16(ah_[i_], bl_, acc[i_][j_]); \
                if (PASSES >= 2) acc[i_][j_] = mfma16(al_[i_], bh_, acc[i_][j_]); \
            }                                                                  \
        }                                                                      \
    }                                                                          \
} while(0)

    STAGE(0, 0);
    __syncthreads();
    int cur = 0;
    for (int s = 0; s < 15; ++s) {
        if (cur == 0) STAGE(1, (s+1)*64);
        else          STAGE(0, (s+1)*64);
        COMPUTE(cur);
        __syncthreads();
        cur ^= 1;
    }
    COMPUTE(cur);
#undef STAGE
#undef COMPUTE

    // ---- epilogue ----
    #pragma unroll
    for (int i = 0; i < 4; ++i)
        #pragma unroll
        for (int j = 0; j < 4; ++j)
            #pragma unroll
            for (int r = 0; r < 4; ++r) {
                const int m = m0 + (wr<<6) + (i<<4) + (l4<<2) + r;
                const int n = n0 + (wc<<6) + (j<<4) + l15;
                const float v = acc[i][j][r];
                if (MODE == 0) {
                    outF[(size_t)m*N + n] = v + bias[n];
                } else if (MODE == 2) {
                    outH[(size_t)m*N + n] = f2bf(v + bias[n]);
                } else if (MODE == 3) {
                    outH[(size_t)m*N + n] = f2bf(v + bias[m]);
                } else {
                    const float pre = v + bias[n] + trust[m]*wlast[n];
                    const float g = 1.f/(1.f + __expf(-pre));
                    const float att = bf2f(attH[(size_t)m*N + n]) + bf2f(attL[(size_t)m*N + n]);
                    const float gated = att*g;
                    const unsigned short hb = f2bf(gated);
                    outH[(size_t)m*N + n] = hb;
                    outL[(size_t)m*N + n] = f2bf(gated - bf2f(hb));
                }
            }
}

// ---------------- Attention v3 (MFMA bf16, precomputed trust bias) ----------------
// Block: 16 q rows x (b,h), 512 threads / 8 waves; wave w owns keys [w*128, w*128+128).
// Trust bias loaded from precomputed bf16 table T[b][q][k] (L2/L3-resident, reused x16 heads).
__global__ __launch_bounds__(512, 4)
void attn_kernel(const u16* __restrict__ Qb, const u16* __restrict__ Kb,
                 const u16* __restrict__ Vt, const u16* __restrict__ T,
                 const int* __restrict__ mask,
                 float* __restrict__ attnOut, u16* __restrict__ attH, u16* __restrict__ attL)
{
    __shared__ float P[16*1024];      // 64 KB score/P strip (aliased for PV reduce)
    __shared__ float redA[8][16];
    __shared__ float redB[8][16];
    __shared__ int   mqv[16];

    const int t    = threadIdx.x;
    const int lane = t & 63, wave = t >> 6;     // 8 waves
    const int l15  = lane & 15, l4 = lane >> 4;
    const int q0   = blockIdx.x * 16, h = blockIdx.y, b = blockIdx.z;
    const int wk0  = wave * 128;

    if (t < 16) mqv[t] = mask[b*SS + q0 + t];

    const u16* Qp = Qb + ((size_t)(b*SS + q0 + l15))*DD + h*HDD + l4*8;
    bf16x8 qf0 = *(const bf16x8*)Qp;
    bf16x8 qf1 = *(const bf16x8*)(Qp + 32);

    // per-row trust-bias base pointers
    const u16* Tb[4];
    #pragma unroll
    for (int r = 0; r < 4; ++r)
        Tb[r] = T + ((size_t)b*SS + q0 + l4*4 + r)*SS + wk0 + l15;

    __syncthreads();

    // ---- QK^T: 8 key tiles of 16 per wave ----
    f32x4 sacc[8];
    #pragma unroll
    for (int tt = 0; tt < 8; ++tt) sacc[tt] = (f32x4){0.f,0.f,0.f,0.f};

    const u16* Kbase = Kb + ((size_t)(b*SS + wk0 + l15))*DD + h*HDD + l4*8;
    #pragma unroll
    for (int tt = 0; tt < 8; ++tt) {
        const u16* Kp = Kbase + (size_t)tt*(16*DD);
        bf16x8 kf0 = *(const bf16x8*)Kp;
        bf16x8 kf1 = *(const bf16x8*)(Kp + 32);
        sacc[tt] = mfma16(qf0, kf0, sacc[tt]);
        sacc[tt] = mfma16(qf1, kf1, sacc[tt]);
    }

    // ---- bias + mask + row-max ----
    int mrow[4];
    #pragma unroll
    for (int r = 0; r < 4; ++r) mrow[r] = mqv[l4*4 + r];

    float mx[4] = {-3e38f, -3e38f, -3e38f, -3e38f};
    #pragma unroll
    for (int tt = 0; tt < 8; ++tt) {
        #pragma unroll
        for (int r = 0; r < 4; ++r) {
            const float bias = bf2f(Tb[r][tt*16]);
            float s = sacc[tt][r]*0.125f + bias;
            s = mrow[r] ? s : -1e9f;
            sacc[tt][r] = s;
            mx[r] = fmaxf(mx[r], s);
        }
    }
    #pragma unroll
    for (int r = 0; r < 4; ++r)
        #pragma unroll
        for (int xm = 1; xm < 16; xm <<= 1) mx[r] = fmaxf(mx[r], __shfl_xor(mx[r], xm));
    if (l15 == 0) {
        #pragma unroll
        for (int r = 0; r < 4; ++r) redA[wave][l4*4 + r] = mx[r];
    }
    __syncthreads();

    float mxa[4];
    #pragma unroll
    for (int r = 0; r < 4; ++r) {
        const int row = l4*4 + r;
        float m = redA[0][row];
        #pragma unroll
        for (int w = 1; w < 8; ++w) m = fmaxf(m, redA[w][row]);
        mxa[r] = m;
    }

    // ---- exp + row-sum; store UNNORMALIZED p to LDS (swizzled) ----
    float sum[4] = {0.f, 0.f, 0.f, 0.f};
    #pragma unroll
    for (int tt = 0; tt < 8; ++tt) {
        const int k = wk0 + tt*16 + l15;
        const int c = k >> 2, j = k & 3;
        #pragma unroll
        for (int r = 0; r < 4; ++r) {
            const int row = l4*4 + r;
            const float p = __expf(sacc[tt][r] - mxa[r]);
            sum[r] += p;
            P[row*1024 + ((c ^ (row & 7)) << 2) + j] = p;
        }
    }
    #pragma unroll
    for (int r = 0; r < 4; ++r)
        #pragma unroll
        for (int xm = 1; xm < 16; xm <<= 1) sum[r] += __shfl_xor(sum[r], xm);
    if (l15 == 0) {
        #pragma unroll
        for (int r = 0; r < 4; ++r) redB[wave][l4*4 + r] = sum[r];
    }
    __syncthreads();

    // ---- stream attn to global (coalesced f32x4, normalized on the fly) ----
    {
        const int row = t >> 5;            // 16 rows, 32 threads each
        const int cl  = t & 31;
        float s8 = 0.f;
        #pragma unroll
        for (int w = 0; w < 8; ++w) s8 += redB[w][row];
        const float iv = 1.f / s8;
        float* gRow = attnOut + ((size_t)(b*HH + h))*SS*SS + (size_t)(q0 + row)*SS;
        #pragma unroll
        for (int i = 0; i < 8; ++i) {
            const int c = cl + i*32;
            f32x4 v = *(f32x4*)&P[row*1024 + ((c ^ (row & 7)) << 2)];
            v *= iv;
            *(f32x4*)&gRow[c*4] = v;
        }
    }

    // ---- per-thread inverse sums for PV rows ----
    float inv4[4];
    #pragma unroll
    for (int r = 0; r < 4; ++r) {
        const int row = l4*4 + r;
        float s8 = 0.f;
        #pragma unroll
        for (int w = 0; w < 8; ++w) s8 += redB[w][row];
        inv4[r] = 1.f / s8;
    }

    // ---- PV: wave's 128-key strip, unnormalized P (bf16-cvt on the fly) ----
    f32x4 pv[4];
    #pragma unroll
    for (int nt = 0; nt < 4; ++nt) pv[nt] = (f32x4){0.f,0.f,0.f,0.f};

    const u16* Vbase = Vt + ((size_t)(h*HDD + l15))*MTOT + b*SS + wk0 + l4*8;
    #pragma unroll
    for (int t2 = 0; t2 < 4; ++t2) {
        const int k  = wk0 + t2*32 + l4*8;
        const int c0 = k >> 2;
        f32x4 a0 = *(f32x4*)&P[l15*1024 + (((c0    ) ^ (l15 & 7)) << 2)];
        f32x4 a1 = *(f32x4*)&P[l15*1024 + (((c0 + 1) ^ (l15 & 7)) << 2)];
        bf16x8 af;
        af[0] = (__bf16)a0[0]; af[1] = (__bf16)a0[1]; af[2] = (__bf16)a0[2]; af[3] = (__bf16)a0[3];
        af[4] = (__bf16)a1[0]; af[5] = (__bf16)a1[1]; af[6] = (__bf16)a1[2]; af[7] = (__bf16)a1[3];
        #pragma unroll
        for (int nt = 0; nt < 4; ++nt) {
            bf16x8 bf = *(const bf16x8*)(Vbase + (size_t)nt*16*MTOT + t2*32);
            pv[nt] = mfma16(af, bf, pv[nt]);
        }
    }
    __syncthreads();   // all P reads done before aliasing

    // ---- cross-wave reduce through LDS (alias P), scaled by 1/sum ----
    float* pw = P + wave*1024;
    #pragma unroll
    for (int nt = 0; nt < 4; ++nt)
        #pragma unroll
        for (int r = 0; r < 4; ++r)
            pw[(l4*4 + r)*64 + nt*16 + l15] = pv[nt][r] * inv4[r];
    __syncthreads();

    {
        const int q = t >> 5, d0 = (t & 31)*2;
        float sx = 0.f, sy = 0.f;
        #pragma unroll
        for (int w = 0; w < 8; ++w) {
            float2 v = *(float2*)&P[w*1024 + q*64 + d0];
            sx += v.x; sy += v.y;
        }
        const size_t off = ((size_t)(b*SS + q0 + q))*DD + h*HDD + d0;
        const unsigned short h0 = f2bf(sx), h1 = f2bf(sy);
        ushort2 hh = {h0, h1};
        ushort2 ll = {f2bf(sx - bf2f(h0)), f2bf(sy - bf2f(h1))};
        *(ushort2*)&attH[off] = hh;
        *(ushort2*)&attL[off] = ll;
    }
}

extern "C" void kernel_launch(void* const* d_in, const int* in_sizes, int n_in,
                              void* d_out, int out_size, void* d_ws, size_t ws_size,
                              hipStream_t stream) {
    const float* x     = (const float*)d_in[0];
    const float* trust = (const float*)d_in[1];
    const int*   mask  = (const int*)  d_in[2];
    const float* Wq    = (const float*)d_in[3];
    const float* bq    = (const float*)d_in[4];
    const float* Wk    = (const float*)d_in[5];
    const float* bk    = (const float*)d_in[6];
    const float* Wv    = (const float*)d_in[7];
    const float* bv    = (const float*)d_in[8];
    const float* Wtp   = (const float*)d_in[9];
    const float* btp   = (const float*)d_in[10];
    const float* Wg    = (const float*)d_in[11];
    const float* bg    = (const float*)d_in[12];
    const float* Wo    = (const float*)d_in[13];
    const float* bo    = (const float*)d_in[14];

    float* out     = (float*)d_out;
    float* attnOut = out + (size_t)MTOT * DD;

    char* ws = (char*)d_ws;
    u16* xh   = (u16*)(ws + (size_t)0*MB);    // 8 MB -> attH later
    u16* xl   = (u16*)(ws + (size_t)8*MB);    // 8 MB -> attL later
    u16* WqTh = (u16*)(ws + (size_t)16*MB);
    u16* WkTh = (u16*)(ws + (size_t)18*MB);
    u16* WvTh = (u16*)(ws + (size_t)20*MB);
    u16* WgTh = (u16*)(ws + (size_t)22*MB);
    u16* WoTh = (u16*)(ws + (size_t)24*MB);
    u16* WoTl = (u16*)(ws + (size_t)26*MB);
    u16* Qbf  = (u16*)(ws + (size_t)28*MB);   // 8 MB -> Gh later
    u16* Kbf  = (u16*)(ws + (size_t)36*MB);   // 8 MB -> Gl later
    u16* Vt   = (u16*)(ws + (size_t)44*MB);   // 8 MB
    u16* Tb   = (u16*)(ws + (size_t)52*MB);   // 8 MB bf16 trust-bias table
    float* tconst = (float*)(ws + (size_t)60*MB);
    u16* attH = xh;
    u16* attL = xl;
    u16* Gh   = Qbf;
    u16* Gl   = Kbf;

    const dim3 blk(256);
    const dim3 tgrid(16, 16);

    tconst_kernel<<<1, 64, 0, stream>>>(Wtp, btp, tconst);
    tbias_kernel<<<dim3(SS, BB), blk, 0, stream>>>(trust, tconst, Tb);
    split_kernel<<<2048, blk, 0, stream>>>(x, xh, xl, MTOT*DD/4);
    tsplit_kernel<<<tgrid, blk, 0, stream>>>(Wq, WqTh, nullptr);
    tsplit_kernel<<<tgrid, blk, 0, stream>>>(Wk, WkTh, nullptr);
    tsplit_kernel<<<tgrid, blk, 0, stream>>>(Wv, WvTh, nullptr);
    tsplit_kernel<<<tgrid, blk, 0, stream>>>(Wg, WgTh, nullptr);
    tsplit_kernel<<<tgrid, blk, 0, stream>>>(Wo, WoTh, WoTl);

    // Q, K: 2-pass (AhBh + AlBh), bf16 out
    mgemm<2,2><<<dim3(DD/128, MTOT/128), blk, 0, stream>>>(
        xh, xl, WqTh, nullptr, bq, nullptr, Qbf, nullptr, MTOT, DD,
        nullptr, nullptr, nullptr, nullptr);
    mgemm<2,2><<<dim3(DD/128, MTOT/128), blk, 0, stream>>>(
        xh, xl, WkTh, nullptr, bk, nullptr, Kbf, nullptr, MTOT, DD,
        nullptr, nullptr, nullptr, nullptr);
    // V^T: 1-pass, C[d_glob][m] = WvT @ x^T (bias by row)
    mgemm<3,1><<<dim3(MTOT/128, DD/128), blk, 0, stream>>>(
        WvTh, nullptr, xh, nullptr, bv, nullptr, Vt, nullptr, DD, MTOT,
        nullptr, nullptr, nullptr, nullptr);

    attn_kernel<<<dim3(SS/16, HH, BB), dim3(512), 0, stream>>>(
        Qbf, Kbf, Vt, Tb, mask, attnOut, attH, attL);

    // gate: 1-pass; gated = attended * sigmoid(attended@Wg[0:1024] + bg + trust*wlast)
    mgemm<1,1><<<dim3(DD/128, MTOT/128), blk, 0, stream>>>(
        attH, nullptr, WgTh, nullptr, bg, nullptr, Gh, Gl, MTOT, DD,
        trust, Wg + (size_t)DD*DD, attH, attL);
    // out = gated @ Wo + bo (fp32, 3-pass)
    mgemm<0,3><<<dim3(DD/128, MTOT/128), blk, 0, stream>>>(
        Gh, Gl, WoTh, WoTl, bo, out, nullptr, nullptr, MTOT, DD,
        nullptr, nullptr, nullptr, nullptr);
}